// Round 7
// baseline (414.933 us; speedup 1.0000x reference)
//
#include <hip/hip_runtime.h>
#include <math.h>

#define VIEWS 8
#define SEQ 2048
#define HID 1024
#define ATT 128
#define QSCALE 0.08838834764831845f  // 128^-0.5

typedef __attribute__((ext_vector_type(8))) short short8;
typedef __attribute__((ext_vector_type(4))) float f32x4;

#define GLOAD_LDS16(g, l)                                                     \
  __builtin_amdgcn_global_load_lds(                                           \
      (const __attribute__((address_space(1))) unsigned int*)(g),             \
      (__attribute__((address_space(3))) unsigned int*)(l), 16, 0, 0)

__device__ __forceinline__ unsigned short f2bf(float f) {
  union { float f; unsigned u; } a; a.f = f;
  unsigned r = a.u + 0x7FFF + ((a.u >> 16) & 1);  // RNE
  return (unsigned short)(r >> 16);
}

// ---------------------------------------------------------------------------
// Transpose + convert fp32 [R][C] -> bf16 [C][R].  R,C multiples of 64.
// ---------------------------------------------------------------------------
__global__ __launch_bounds__(256)
void transpose_cvt_f32_bf16(const float* __restrict__ in,
                            unsigned short* __restrict__ out, int R, int C) {
  __shared__ alignas(16) unsigned short T[64][72];
  const int tid = threadIdx.x;
  const int r0 = blockIdx.y * 64, c0 = blockIdx.x * 64;
  const int tr = tid >> 2, tc = (tid & 3) * 16;
#pragma unroll
  for (int u = 0; u < 4; ++u) {
    float4 t = *(const float4*)&in[(size_t)(r0 + tr) * C + c0 + tc + u * 4];
    T[tc + u * 4 + 0][tr] = f2bf(t.x);
    T[tc + u * 4 + 1][tr] = f2bf(t.y);
    T[tc + u * 4 + 2][tr] = f2bf(t.z);
    T[tc + u * 4 + 3][tr] = f2bf(t.w);
  }
  __syncthreads();
  const int oc = tid >> 2, orr = (tid & 3) * 16;
#pragma unroll
  for (int u = 0; u < 2; ++u)
    *(short8*)&out[(size_t)(c0 + oc) * R + r0 + orr + u * 8] =
        *(const short8*)&T[oc][orr + u * 8];
}

// Batched variant for wq/wk/wv (z selects). R=1024, C=128. grid (2,16,3).
__global__ __launch_bounds__(256)
void transpose_qkvw(const float* __restrict__ wq, const float* __restrict__ wk,
                    const float* __restrict__ wv, unsigned short* __restrict__ oq,
                    unsigned short* __restrict__ ok, unsigned short* __restrict__ ov) {
  __shared__ alignas(16) unsigned short T[64][72];
  const int z = blockIdx.z;
  const float* in = (z == 0) ? wq : (z == 1) ? wk : wv;
  unsigned short* out = (z == 0) ? oq : (z == 1) ? ok : ov;
  const int R = HID, C = ATT;
  const int tid = threadIdx.x;
  const int r0 = blockIdx.y * 64, c0 = blockIdx.x * 64;
  const int tr = tid >> 2, tc = (tid & 3) * 16;
#pragma unroll
  for (int u = 0; u < 4; ++u) {
    float4 t = *(const float4*)&in[(size_t)(r0 + tr) * C + c0 + tc + u * 4];
    T[tc + u * 4 + 0][tr] = f2bf(t.x);
    T[tc + u * 4 + 1][tr] = f2bf(t.y);
    T[tc + u * 4 + 2][tr] = f2bf(t.z);
    T[tc + u * 4 + 3][tr] = f2bf(t.w);
  }
  __syncthreads();
  const int oc = tid >> 2, orr = (tid & 3) * 16;
#pragma unroll
  for (int u = 0; u < 2; ++u)
    *(short8*)&out[(size_t)(c0 + oc) * R + r0 + orr + u * 8] =
        *(const short8*)&T[oc][orr + u * 8];
}

// ---------------------------------------------------------------------------
// Fused QKV projection — global_load_lds staging, XOR bank swizzle (R6),
// now with COUNTED-vmcnt 3-buffer depth-2 pipeline (T4): the per-iter wait
// is vmcnt(6) (oldest tile's 6 DMAs done; newest 6 stay in flight across
// the barrier) — never a full drain until the last iteration.
//   buf hazard: STAGE(kk+2) writes buf[(kk-1)%3]; all ds_reads of it
//   completed before their wave reached this barrier (lgkmcnt precedes
//   the MFMA uses, which precede the barrier in program order).
// m-tile 32, 4 waves = 2m x 2n; LDS 72 KB -> 2 blocks/CU; grid (512,1,3).
// ---------------------------------------------------------------------------
__global__ __launch_bounds__(256, 2)
void qkv_proj(const float* __restrict__ q, const float* __restrict__ k,
              const float* __restrict__ v, const unsigned short* __restrict__ wqT,
              const unsigned short* __restrict__ wkT,
              const unsigned short* __restrict__ wvT,
              const float* __restrict__ bq, const float* __restrict__ bk,
              const float* __restrict__ bv, unsigned short* __restrict__ qh,
              unsigned short* __restrict__ kh, unsigned short* __restrict__ vhT) {
  __shared__ alignas(16) float Af[3][32][64];
  __shared__ alignas(16) unsigned short Bf[3][128][64];
  const int z = blockIdx.z;
  const float* A = (z == 0) ? q : (z == 1) ? k : v;
  const unsigned short* B = (z == 0) ? wqT : (z == 1) ? wkT : wvT;
  const float* bias = (z == 0) ? bq : (z == 1) ? bk : bv;
  const float scale = (z == 0) ? QSCALE : 1.0f;
  const int tid = threadIdx.x;
  const int w = tid >> 6, lane = tid & 63;
  const int l16 = lane & 15, quad = lane >> 4;
  const int m0 = blockIdx.x * 32;
  const int wm = (w & 1) * 16;     // wave's 16-row q-slab
  const int n0 = (w >> 1) * 64;    // wave's 64-col half of ATT

  // A DMA chunks: chunk c = w*2+j covers rows c*4..c*4+3 (1 KB).
  //   lane -> row r = c*4+(lane>>4), LDS slot p = lane&15 (16B granule).
  //   source granule = p ^ (r&7)   (inverse swizzle at the source)
  const float* ag[2];
#pragma unroll
  for (int j = 0; j < 2; ++j) {
    const int c = w * 2 + j;
    const int r = c * 4 + (lane >> 4);
    const int sg = (lane & 15) ^ (r & 7);
    ag[j] = &A[(size_t)(m0 + r) * HID + sg * 4];
  }
  // B DMA chunks: chunk c = w*4+j covers rows c*8..c*8+7 (1 KB).
  //   lane -> row r = c*8+(lane>>3), slot p = lane&7; source granule p^(r&7).
  const unsigned short* bg[4];
#pragma unroll
  for (int j = 0; j < 4; ++j) {
    const int c = w * 4 + j;
    const int r = c * 8 + (lane >> 3);
    const int sg = (lane & 7) ^ (r & 7);
    bg[j] = &B[(size_t)r * HID + sg * 8];
  }

  f32x4 acc[4];
#pragma unroll
  for (int i = 0; i < 4; ++i) acc[i] = (f32x4)0.f;

#define QKV_STAGE(nxt, k0)                                                    \
  do {                                                                        \
    _Pragma("unroll") for (int j = 0; j < 2; ++j)                             \
        GLOAD_LDS16(ag[j] + (k0), &Af[nxt][(w * 2 + j) * 4][0]);              \
    _Pragma("unroll") for (int j = 0; j < 4; ++j)                             \
        GLOAD_LDS16(bg[j] + (k0), &Bf[nxt][(w * 4 + j) * 8][0]);              \
  } while (0)

  // prologue: stage tiles 0 and 1 (12 DMAs outstanding per wave)
  QKV_STAGE(0, 0);
  QKV_STAGE(1, 64);
  int cur = 0, nx = 2;
  const int akey = l16 & 7;  // swizzle key for all fragment rows (row&7==l16&7)
#pragma unroll 1
  for (int kk = 0; kk < HID / 64; ++kk) {
    // counted wait: oldest 6 DMAs (tile kk) done; tile kk+1's 6 stay in flight
    if (kk < HID / 64 - 1) {
      asm volatile("s_waitcnt vmcnt(6)" ::: "memory");
    } else {
      asm volatile("s_waitcnt vmcnt(0)" ::: "memory");
    }
    __builtin_amdgcn_s_barrier();
    __builtin_amdgcn_sched_barrier(0);
    if (kk + 2 < HID / 64) QKV_STAGE(nx, (kk + 2) * 64);
    // A fragments: fp32 granules {quad*2, quad*2+1, quad*2+8, quad*2+9},
    // each fetched from swizzled slot g^akey.
    const float4 a0 = *(const float4*)&Af[cur][wm + l16][((quad * 2)     ^ akey) * 4];
    const float4 a1 = *(const float4*)&Af[cur][wm + l16][((quad * 2 + 1) ^ akey) * 4];
    const float4 a2 = *(const float4*)&Af[cur][wm + l16][((quad * 2 + 8) ^ akey) * 4];
    const float4 a3 = *(const float4*)&Af[cur][wm + l16][((quad * 2 + 9) ^ akey) * 4];
    short8 af0, af1;
    af0[0] = (short)f2bf(a0.x); af0[1] = (short)f2bf(a0.y);
    af0[2] = (short)f2bf(a0.z); af0[3] = (short)f2bf(a0.w);
    af0[4] = (short)f2bf(a1.x); af0[5] = (short)f2bf(a1.y);
    af0[6] = (short)f2bf(a1.z); af0[7] = (short)f2bf(a1.w);
    af1[0] = (short)f2bf(a2.x); af1[1] = (short)f2bf(a2.y);
    af1[2] = (short)f2bf(a2.z); af1[3] = (short)f2bf(a2.w);
    af1[4] = (short)f2bf(a3.x); af1[5] = (short)f2bf(a3.y);
    af1[6] = (short)f2bf(a3.z); af1[7] = (short)f2bf(a3.w);
#pragma unroll
    for (int nt = 0; nt < 4; ++nt) {
      const int brow = n0 + nt * 16 + l16;
      const short8 b0 = *(const short8*)&Bf[cur][brow][((quad)     ^ akey) * 8];
      const short8 b1 = *(const short8*)&Bf[cur][brow][((quad + 4) ^ akey) * 8];
      acc[nt] = __builtin_amdgcn_mfma_f32_16x16x32_bf16(af0, b0, acc[nt], 0, 0, 0);
      acc[nt] = __builtin_amdgcn_mfma_f32_16x16x32_bf16(af1, b1, acc[nt], 0, 0, 0);
    }
    cur = (cur + 1 == 3) ? 0 : cur + 1;
    nx  = (nx + 1 == 3) ? 0 : nx + 1;
  }
#undef QKV_STAGE

  if (z < 2) {
    unsigned short* outp = (z == 0) ? qh : kh;
#pragma unroll
    for (int nt = 0; nt < 4; ++nt) {
      const int col = n0 + nt * 16 + l16;
      const float bvv = bias[col];
#pragma unroll
      for (int reg = 0; reg < 4; ++reg) {
        const int row = m0 + wm + quad * 4 + reg;
        outp[(size_t)row * ATT + col] = f2bf((acc[nt][reg] + bvv) * scale);
      }
    }
  } else {
    // transposed store: vhT[vi][a][s]; 4 consecutive rows share vi (32 | 2048)
    const int gr = m0 + wm + quad * 4;
    const int vi = gr >> 11, s = gr & (SEQ - 1);
#pragma unroll
    for (int nt = 0; nt < 4; ++nt) {
      const int col = n0 + nt * 16 + l16;
      const float bvv = bias[col];
      ushort4 pk;
      pk.x = f2bf(acc[nt][0] + bvv);
      pk.y = f2bf(acc[nt][1] + bvv);
      pk.z = f2bf(acc[nt][2] + bvv);
      pk.w = f2bf(acc[nt][3] + bvv);
      *(ushort4*)&vhT[((size_t)vi * ATT + col) * SEQ + s] = pk;
    }
  }
}

// ---------------------------------------------------------------------------
// Fused flash attention + post-softmax-bias@V, min-2-phase pipelined
// (verified 64-row version).
// grid (VIEWS, SEQ/64); LDS = 96 KB -> 1 block/CU.
// ---------------------------------------------------------------------------
__global__ __launch_bounds__(256, 1)
void flash_fused(const unsigned short* __restrict__ qh,
                 const unsigned short* __restrict__ kh,
                 const unsigned short* __restrict__ vhT,
                 const float* __restrict__ ab,
                 unsigned short* __restrict__ xbf) {
  __shared__ alignas(16) unsigned short Qs[64][136];
  __shared__ alignas(16) unsigned short Ks[2][64][136];
  __shared__ alignas(16) unsigned short VTs[2][128][72];
  __shared__ alignas(16) unsigned short Ps[64][72];
  const int tid = threadIdx.x;
  const int vi = blockIdx.x;
  const int q0 = blockIdx.y * 64;
  const int w = tid >> 6, lane = tid & 63;
  const int l16 = lane & 15, quad = lane >> 4;
  const int wb = w * 16;

  // staging coordinates
  const int kr_ = tid >> 2, kc_ = (tid & 3) * 32;   // K tile [64 keys][128]
  const int vr_ = tid >> 1, vc_ = (tid & 1) * 32;   // V^T tile [128 a][64 keys]
  const unsigned short* kbase = &kh[((size_t)vi * SEQ + kr_) * ATT + kc_];
  const unsigned short* vbase = &vhT[((size_t)vi * ATT + vr_) * SEQ + vc_];

  {  // stage Q tile once
    const int r = tid >> 2, c = (tid & 3) * 32;
    const unsigned short* src = &qh[((size_t)vi * SEQ + q0 + r) * ATT + c];
#pragma unroll
    for (int u = 0; u < 4; ++u)
      *(short8*)&Qs[r][c + u * 8] = *(const short8*)&src[u * 8];
  }

  // prologue: issue K/V loads for tile 0 into regs
  short8 krg[4], vrg[4];
#pragma unroll
  for (int u = 0; u < 4; ++u) krg[u] = *(const short8*)&kbase[u * 8];
#pragma unroll
  for (int u = 0; u < 4; ++u) vrg[u] = *(const short8*)&vbase[u * 8];

  __syncthreads();  // Qs visible
  short8 aF[4];
#pragma unroll
  for (int ks = 0; ks < 4; ++ks)
    aF[ks] = *(const short8*)&Qs[wb + l16][ks * 32 + quad * 8];

  float l_r[4] = {0.f, 0.f, 0.f, 0.f};
  f32x4 o[8], o2[8];
#pragma unroll
  for (int i = 0; i < 8; ++i) { o[i] = (f32x4)0.f; o2[i] = (f32x4)0.f; }

  const float* abrow = &ab[((size_t)vi * SEQ + q0 + wb + l16) * SEQ];

  for (int t = 0; t < SEQ / 64; ++t) {
    const int kt = t * 64;
    const int cur = t & 1;
    // bias fragment loads for tile t (issued early, consumed in PV phase)
    float4 abv[4];
    abv[0] = *(const float4*)&abrow[kt + quad * 8];
    abv[1] = *(const float4*)&abrow[kt + quad * 8 + 4];
    abv[2] = *(const float4*)&abrow[kt + 32 + quad * 8];
    abv[3] = *(const float4*)&abrow[kt + 32 + quad * 8 + 4];
    // ---- write staged regs (tile t) into LDS buf[cur]
#pragma unroll
    for (int u = 0; u < 4; ++u)
      *(short8*)&Ks[cur][kr_][kc_ + u * 8] = krg[u];
#pragma unroll
    for (int u = 0; u < 4; ++u)
      *(short8*)&VTs[cur][vr_][vc_ + u * 8] = vrg[u];
    __syncthreads();
    // ---- issue K/V loads for tile t+1 (fly under the MFMA phase)
    if (t + 1 < SEQ / 64) {
      const unsigned short* kp = kbase + (size_t)(kt + 64) * ATT;
      const unsigned short* vp = vbase + (kt + 64);
#pragma unroll
      for (int u = 0; u < 4; ++u) krg[u] = *(const short8*)&kp[u * 8];
#pragma unroll
      for (int u = 0; u < 4; ++u) vrg[u] = *(const short8*)&vp[u * 8];
    }
    // ---- QK^T
    f32x4 sc[4];
#pragma unroll
    for (int i = 0; i < 4; ++i) sc[i] = (f32x4)0.f;
#pragma unroll
    for (int nt = 0; nt < 4; ++nt) {
#pragma unroll
      for (int ks = 0; ks < 4; ++ks) {
        short8 bF = *(const short8*)&Ks[cur][nt * 16 + l16][ks * 32 + quad * 8];
        sc[nt] = __builtin_amdgcn_mfma_f32_16x16x32_bf16(aF[ks], bF, sc[nt], 0, 0, 0);
      }
    }
    // ---- p = exp(s); accumulate partial l per lane (no shuffles)
#pragma unroll
    for (int nt = 0; nt < 4; ++nt) {
#pragma unroll
      for (int reg = 0; reg < 4; ++reg) {
        float p = __expf(sc[nt][reg]);
        l_r[reg] += p;
        Ps[wb + quad * 4 + reg][nt * 16 + l16] = f2bf(p);
      }
    }
    // ---- PV + bias@V sharing V fragments
#pragma unroll
    for (int ks = 0; ks < 2; ++ks) {
      short8 pF = *(const short8*)&Ps[wb + l16][ks * 32 + quad * 8];
      short8 bB;
      {
        const float4 u0 = abv[ks * 2], u1 = abv[ks * 2 + 1];
        bB[0] = (short)f2bf(u0.x); bB[1] = (short)f2bf(u0.y);
        bB[2] = (short)f2bf(u0.z); bB[3] = (short)f2bf(u0.w);
        bB[4] = (short)f2bf(u1.x); bB[5] = (short)f2bf(u1.y);
        bB[6] = (short)f2bf(u1.z); bB[7] = (short)f2bf(u1.w);
      }
#pragma unroll
      for (int at = 0; at < 8; ++at) {
        short8 vF = *(const short8*)&VTs[cur][at * 16 + l16][ks * 32 + quad * 8];
        o[at]  = __builtin_amdgcn_mfma_f32_16x16x32_bf16(pF, vF, o[at], 0, 0, 0);
        o2[at] = __builtin_amdgcn_mfma_f32_16x16x32_bf16(bB, vF, o2[at], 0, 0, 0);
      }
    }
  }
  // final l reduction across the 16 l16-lanes, then epilogue
  float inv_l[4];
#pragma unroll
  for (int reg = 0; reg < 4; ++reg) {
    float l = l_r[reg];
    l += __shfl_xor(l, 1, 64);
    l += __shfl_xor(l, 2, 64);
    l += __shfl_xor(l, 4, 64);
    l += __shfl_xor(l, 8, 64);
    inv_l[reg] = 1.0f / l;
  }
#pragma unroll
  for (int at = 0; at < 8; ++at) {
    const int col = vi * ATT + at * 16 + l16;
#pragma unroll
    for (int reg = 0; reg < 4; ++reg) {
      const int row = q0 + wb + quad * 4 + reg;
      xbf[(size_t)row * HID + col] = f2bf(o[at][reg] * inv_l[reg] + o2[at][reg]);
    }
  }
}

// ---------------------------------------------------------------------------
// Out projection: out[2048][1024] = xbf[2048][1024](bf16) @ wo + bo  (fp32)
// grid (32, 8), m-tile 64, n-tile 128, K=1024.  Min-2-phase pipelined.
// ---------------------------------------------------------------------------
__global__ __launch_bounds__(256)
void outproj_gemm(const unsigned short* __restrict__ A,
                  const unsigned short* __restrict__ B,  // woT [n][k]
                  const float* __restrict__ bias, float* __restrict__ out) {
  __shared__ alignas(16) unsigned short As[2][64][72];
  __shared__ alignas(16) unsigned short Bs[2][128][72];
  const int tid = threadIdx.x;
  const int m0 = blockIdx.x * 64;
  const int n0 = blockIdx.y * 128;
  const int w = tid >> 6, lane = tid & 63;
  const int l16 = lane & 15, quad = lane >> 4;
  const int ar = tid >> 2, ac = (tid & 3) * 16;
  const int br = tid >> 1, bc = (tid & 1) * 32;
  const unsigned short* abase = &A[(size_t)(m0 + ar) * HID + ac];
  const unsigned short* bbase = &B[(size_t)(n0 + br) * HID + bc];

  f32x4 acc[8];
#pragma unroll
  for (int i = 0; i < 8; ++i) acc[i] = (f32x4)0.f;

  // prologue: issue loads for k-tile 0
  short8 arg0, arg1, brg[4];
  arg0 = *(const short8*)&abase[0];
  arg1 = *(const short8*)&abase[8];
#pragma unroll
  for (int u = 0; u < 4; ++u) brg[u] = *(const short8*)&bbase[u * 8];

  for (int kk = 0; kk < HID / 64; ++kk) {
    const int cur = kk & 1;
    // write staged regs into LDS buf[cur]
    *(short8*)&As[cur][ar][ac]     = arg0;
    *(short8*)&As[cur][ar][ac + 8] = arg1;
#pragma unroll
    for (int u = 0; u < 4; ++u)
      *(short8*)&Bs[cur][br][bc + u * 8] = brg[u];
    __syncthreads();
    // issue loads for k-tile kk+1
    if (kk + 1 < HID / 64) {
      const unsigned short* ap = abase + (kk + 1) * 64;
      const unsigned short* bp = bbase + (kk + 1) * 64;
      arg0 = *(const short8*)&ap[0];
      arg1 = *(const short8*)&ap[8];
#pragma unroll
      for (int u = 0; u < 4; ++u) brg[u] = *(const short8*)&bp[u * 8];
    }
    // compute from buf[cur]
#pragma unroll
    for (int ks = 0; ks < 2; ++ks) {
      short8 af = *(const short8*)&As[cur][w * 16 + l16][ks * 32 + quad * 8];
#pragma unroll
      for (int nt = 0; nt < 8; ++nt) {
        short8 bf = *(const short8*)&Bs[cur][nt * 16 + l16][ks * 32 + quad * 8];
        acc[nt] = __builtin_amdgcn_mfma_f32_16x16x32_bf16(af, bf, acc[nt], 0, 0, 0);
      }
    }
  }
#pragma unroll
  for (int nt = 0; nt < 8; ++nt) {
    const int col = n0 + nt * 16 + l16;
    const float bvv = bias[col];
#pragma unroll
    for (int reg = 0; reg < 4; ++reg) {
      const int row = m0 + w * 16 + quad * 4 + reg;
      out[(size_t)row * HID + col] = acc[nt][reg] + bvv;
    }
  }
}

// ---------------------------------------------------------------------------
extern "C" void kernel_launch(void* const* d_in, const int* in_sizes, int n_in,
                              void* d_out, int out_size, void* d_ws, size_t ws_size,
                              hipStream_t stream) {
  const float* q   = (const float*)d_in[0];
  const float* k   = (const float*)d_in[1];
  const float* v   = (const float*)d_in[2];
  const float* ab  = (const float*)d_in[3];
  const float* wq  = (const float*)d_in[4];
  const float* bq  = (const float*)d_in[5];
  const float* wk  = (const float*)d_in[6];
  const float* bk  = (const float*)d_in[7];
  const float* wv  = (const float*)d_in[8];
  const float* bv  = (const float*)d_in[9];
  const float* wo  = (const float*)d_in[10];
  const float* bo  = (const float*)d_in[11];
  float* out = (float*)d_out;

  char* ws = (char*)d_ws;
  const size_t PROJ_B = (size_t)VIEWS * SEQ * ATT * 2;  // 4 MB bf16
  unsigned short* qh  = (unsigned short*)(ws);
  unsigned short* kh  = (unsigned short*)(ws + PROJ_B);
  unsigned short* vhT = (unsigned short*)(ws + 2 * PROJ_B);
  unsigned short* xbf = (unsigned short*)(ws + 3 * PROJ_B);
  char* wbase = ws + 4 * PROJ_B;
  unsigned short* wqT = (unsigned short*)(wbase);
  unsigned short* wkT = (unsigned short*)(wbase + 262144);
  unsigned short* wvT = (unsigned short*)(wbase + 2 * 262144);
  unsigned short* woT = (unsigned short*)(wbase + 3 * 262144);

  dim3 blk(256);
  transpose_qkvw<<<dim3(2, 16, 3), blk, 0, stream>>>(wq, wk, wv, wqT, wkT, wvT);
  transpose_cvt_f32_bf16<<<dim3(16, 16), blk, 0, stream>>>(wo, woT, HID, HID);
  qkv_proj<<<dim3(512, 1, 3), blk, 0, stream>>>(q, k, v, wqT, wkT, wvT,
                                                bq, bk, bv, qh, kh, vhT);
  flash_fused<<<dim3(VIEWS, SEQ / 64), blk, 0, stream>>>(qh, kh, vhT, ab, xbf);
  outproj_gemm<<<dim3(SEQ / 64, HID / 128), blk, 0, stream>>>(xbf, woT, bo, out);
}